// Round 1
// baseline (272.231 us; speedup 1.0000x reference)
//
#include <hip/hip_runtime.h>

#define Bn 4
#define Qn 128
#define Kn 1024
#define Dn 512   // DQ = DK = DV = 512
#define Hn 256

// tanh(x) = 1 - 2/(1 + e^{2x}).  Inf-safe: e->inf => rcp(inf)=0 => 1; e->0 => -1.
__device__ __forceinline__ float fast_tanh(float x) {
    float e = __expf(2.0f * x);                       // v_mul + v_exp_f32
    return 1.0f - 2.0f * __builtin_amdgcn_rcpf(1.0f + e);
}

// ---------------------------------------------------------------------------
// Kernel 1: projections. 8 rows per block to amortize W column loads (L2).
// blocks 0..63   -> q rows (512 rows of queries @ Wq)
// blocks 64..575 -> k rows (4096 rows of keys @ Wk), early-exit past valid_len
// ---------------------------------------------------------------------------
__global__ __launch_bounds__(256) void proj_kernel(
    const float* __restrict__ queries, const float* __restrict__ keys,
    const float* __restrict__ Wq, const float* __restrict__ Wk,
    const int* __restrict__ valid_lens,
    float* __restrict__ qproj, float* __restrict__ kproj)
{
    const int blk = blockIdx.x;
    const int t = threadIdx.x;
    const float* in; const float* W; float* out;
    if (blk < 64) {
        int r0 = blk * 8;
        in = queries + r0 * Dn;  W = Wq;  out = qproj + r0 * Hn;
    } else {
        int r0 = (blk - 64) * 8;            // 0..4095 over [B,K]
        int b = r0 >> 10;
        int k0 = r0 & 1023;
        if (k0 >= valid_lens[b]) return;    // masked columns never used
        in = keys + r0 * Dn;  W = Wk;  out = kproj + r0 * Hn;
    }
    __shared__ float s_in[8 * Dn];          // 16 KB
    {
        const float4* inv4 = reinterpret_cast<const float4*>(in);
        float4* sv4 = reinterpret_cast<float4*>(s_in);
        #pragma unroll
        for (int i = 0; i < 4; ++i)         // 8*512/4 = 1024 float4 / 256 thr
            sv4[t + i * 256] = inv4[t + i * 256];
    }
    __syncthreads();
    float acc[8] = {0.f,0.f,0.f,0.f,0.f,0.f,0.f,0.f};
    #pragma unroll 4
    for (int d = 0; d < Dn; ++d) {
        float w = W[d * Hn + t];            // coalesced across threads; L2-resident
        #pragma unroll
        for (int j = 0; j < 8; ++j)
            acc[j] += s_in[j * Dn + d] * w; // LDS broadcast reads
    }
    #pragma unroll
    for (int j = 0; j < 8; ++j)
        out[j * Hn + t] = acc[j];
}

// ---------------------------------------------------------------------------
// Kernel 2: scores + masked softmax fused. One block per (b,q) row.
// Wave w computes scores for k in [w*256, w*256+256) ∩ [0, vlen).
// Lane l holds h = 4l..4l+3 of the q-row and wv; k-row read as float4
// (coalesced 1KB per wave per k). 64-lane butterfly reduce per score.
// ---------------------------------------------------------------------------
__global__ __launch_bounds__(256) void score_softmax_kernel(
    const float* __restrict__ qproj, const float* __restrict__ kproj,
    const float* __restrict__ wv, const int* __restrict__ valid_lens,
    float* __restrict__ attn)
{
    const int row = blockIdx.x;             // b*Q + q
    const int b = row >> 7;                 // Q = 128
    const int t = threadIdx.x;
    const int lane = t & 63;
    const int wave = t >> 6;
    const int vlen = valid_lens[b];

    __shared__ float s_sc[Kn];              // 4 KB scores
    __shared__ float s_red[16];

    const float4 qv  = reinterpret_cast<const float4*>(qproj + row * Hn)[lane];
    const float4 wvv = reinterpret_cast<const float4*>(wv)[lane];

    const float* kb = kproj + b * Kn * Hn;
    const int k0 = wave * 256;
    const int kend = min(vlen, k0 + 256);
    for (int k = k0; k < kend; ++k) {
        float4 kv = reinterpret_cast<const float4*>(kb + k * Hn)[lane];
        float s = wvv.x * fast_tanh(qv.x + kv.x)
                + wvv.y * fast_tanh(qv.y + kv.y)
                + wvv.z * fast_tanh(qv.z + kv.z)
                + wvv.w * fast_tanh(qv.w + kv.w);
        #pragma unroll
        for (int off = 32; off; off >>= 1)
            s += __shfl_xor(s, off, 64);
        if (lane == 0) s_sc[k] = s;
    }
    __syncthreads();

    // softmax over k in [0, vlen); masked entries contribute exactly 0
    float v[4];
    float m = -1e30f;
    #pragma unroll
    for (int j = 0; j < 4; ++j) {
        int k = t + j * 256;
        v[j] = (k < vlen) ? s_sc[k] : -1e30f;
        m = fmaxf(m, v[j]);
    }
    #pragma unroll
    for (int off = 32; off; off >>= 1)
        m = fmaxf(m, __shfl_xor(m, off, 64));
    if (lane == 0) s_red[wave] = m;
    __syncthreads();
    m = fmaxf(fmaxf(s_red[0], s_red[1]), fmaxf(s_red[2], s_red[3]));

    float sum = 0.f;
    #pragma unroll
    for (int j = 0; j < 4; ++j) {
        v[j] = __expf(v[j] - m);            // exp(-1e30 - m) flushes to 0
        sum += v[j];
    }
    #pragma unroll
    for (int off = 32; off; off >>= 1)
        sum += __shfl_xor(sum, off, 64);
    if (lane == 0) s_red[8 + wave] = sum;
    __syncthreads();
    sum = s_red[8] + s_red[9] + s_red[10] + s_red[11];

    const float inv = __builtin_amdgcn_rcpf(sum);
    float* arow = attn + row * Kn;
    #pragma unroll
    for (int j = 0; j < 4; ++j) {
        int k = t + j * 256;
        if (k < vlen) arow[k] = v[j] * inv;
    }
}

// ---------------------------------------------------------------------------
// Kernel 3: out = attn @ values. Block = (b, q-tile of 4, d-half of 256).
// attn tile staged in LDS (broadcast reads); values loads coalesced.
// Loop bounded by vlen (masked attn is exactly 0 and never read).
// ---------------------------------------------------------------------------
#define QT 4
__global__ __launch_bounds__(256) void av_kernel(
    const float* __restrict__ attn, const float* __restrict__ values,
    const int* __restrict__ valid_lens, float* __restrict__ out)
{
    const int blk = blockIdx.x;             // 256 blocks: b(2) | qtile(5) | dhalf(1)
    const int dhalf = blk & 1;
    const int qt = (blk >> 1) & 31;
    const int b = blk >> 6;
    const int t = threadIdx.x;
    const int vlen = valid_lens[b];
    const int q0 = qt * QT;

    __shared__ float s_at[QT][Kn];          // 16 KB
    #pragma unroll
    for (int j = 0; j < QT; ++j)
        for (int k = t; k < vlen; k += 256)
            s_at[j][k] = attn[(b * Qn + q0 + j) * Kn + k];
    __syncthreads();

    const float* vb = values + (size_t)b * Kn * Dn + dhalf * 256 + t;
    float acc[QT] = {0.f, 0.f, 0.f, 0.f};
    for (int k = 0; k < vlen; ++k) {
        float vv = vb[(size_t)k * Dn];
        #pragma unroll
        for (int j = 0; j < QT; ++j)
            acc[j] += s_at[j][k] * vv;
    }
    #pragma unroll
    for (int j = 0; j < QT; ++j)
        out[(b * Qn + q0 + j) * Dn + dhalf * 256 + t] = acc[j];
}

// ---------------------------------------------------------------------------
extern "C" void kernel_launch(void* const* d_in, const int* in_sizes, int n_in,
                              void* d_out, int out_size, void* d_ws, size_t ws_size,
                              hipStream_t stream) {
    const float* queries    = (const float*)d_in[0];
    const float* keys       = (const float*)d_in[1];
    const float* values     = (const float*)d_in[2];
    const int*   valid_lens = (const int*)  d_in[3];
    const float* Wq         = (const float*)d_in[4];
    const float* Wk         = (const float*)d_in[5];
    const float* wv         = (const float*)d_in[6];
    float* out = (float*)d_out;

    float* qproj = (float*)d_ws;                  // [B*Q, H]  = 131072 f
    float* kproj = qproj + Bn * Qn * Hn;          // [B*K, H]  = 1048576 f
    float* attn  = kproj + Bn * Kn * Hn;          // [B*Q, K]  = 524288 f

    proj_kernel<<<576, 256, 0, stream>>>(queries, keys, Wq, Wk, valid_lens,
                                         qproj, kproj);
    score_softmax_kernel<<<Bn * Qn, 256, 0, stream>>>(qproj, kproj, wv,
                                                      valid_lens, attn);
    av_kernel<<<256, 256, 0, stream>>>(attn, values, valid_lens, out);
}

// Round 2
// 184.234 us; speedup vs baseline: 1.4776x; 1.4776x over previous
//
#include <hip/hip_runtime.h>

#define Bn 4
#define Qn 128
#define Kn 1024
#define Dn 512   // DQ = DK = DV = 512
#define Hn 256

// tanh(x) = 1 - 2/(1 + e^{2x}).  Inf-safe: e->inf => rcp(inf)=0 => 1; e->0 => -1.
__device__ __forceinline__ float fast_tanh(float x) {
    float e = __expf(2.0f * x);
    return 1.0f - 2.0f * __builtin_amdgcn_rcpf(1.0f + e);
}

// ---------------------------------------------------------------------------
// Kernel 1: projections (unchanged from R0 — isolate score/av changes; its
// counters will appear in top-5 next round).
// ---------------------------------------------------------------------------
__global__ __launch_bounds__(256) void proj_kernel(
    const float* __restrict__ queries, const float* __restrict__ keys,
    const float* __restrict__ Wq, const float* __restrict__ Wk,
    const int* __restrict__ valid_lens,
    float* __restrict__ qproj, float* __restrict__ kproj)
{
    const int blk = blockIdx.x;
    const int t = threadIdx.x;
    const float* in; const float* W; float* out;
    if (blk < 64) {
        int r0 = blk * 8;
        in = queries + r0 * Dn;  W = Wq;  out = qproj + r0 * Hn;
    } else {
        int r0 = (blk - 64) * 8;            // 0..4095 over [B,K]
        int b = r0 >> 10;
        int k0 = r0 & 1023;
        if (k0 >= valid_lens[b]) return;    // masked columns never used
        in = keys + r0 * Dn;  W = Wk;  out = kproj + r0 * Hn;
    }
    __shared__ float s_in[8 * Dn];          // 16 KB
    {
        const float4* inv4 = reinterpret_cast<const float4*>(in);
        float4* sv4 = reinterpret_cast<float4*>(s_in);
        #pragma unroll
        for (int i = 0; i < 4; ++i)
            sv4[t + i * 256] = inv4[t + i * 256];
    }
    __syncthreads();
    float acc[8] = {0.f,0.f,0.f,0.f,0.f,0.f,0.f,0.f};
    #pragma unroll 4
    for (int d = 0; d < Dn; ++d) {
        float w = W[d * Hn + t];
        #pragma unroll
        for (int j = 0; j < 8; ++j)
            acc[j] += s_in[j * Dn + d] * w;
    }
    #pragma unroll
    for (int j = 0; j < 8; ++j)
        out[j * Hn + t] = acc[j];
}

// ---------------------------------------------------------------------------
// Kernel 2: raw scores. Block = (b, 4-q tile, 32-k tile), 256 threads.
// Wave w owns q-row q0+w. Lane pair (l, l+32) owns score (q, k0 + (l&31)):
// lane l does h in [0,128), lane l+32 does h in [128,256); one shfl_xor(32)
// combines. k-tile in LDS padded to 260 floats/row: float4 reads start at
// bank (4*kloc + h)%32 -> max 4-way conflict (~1.58x), no reductions in loop.
// ---------------------------------------------------------------------------
#define SK_KT 32
#define SK_QT 4
#define SK_PAD 260

__global__ __launch_bounds__(256) void score_kernel(
    const float* __restrict__ qproj, const float* __restrict__ kproj,
    const float* __restrict__ wv, const int* __restrict__ valid_lens,
    float* __restrict__ scores)
{
    const int blk = blockIdx.x;             // b(2) | qt(5) | kt(5)
    const int kt = blk & 31;
    const int qt = (blk >> 5) & 31;
    const int b  = blk >> 10;
    const int vlen = valid_lens[b];
    const int k0 = kt * SK_KT;
    if (k0 >= vlen) return;                 // fully-masked tile: attn==0, skip
    const int q0 = qt * SK_QT;
    const int t = threadIdx.x;

    __shared__ float s_k[SK_KT * SK_PAD];   // 33280 B
    __shared__ float s_q[SK_QT * Hn];       // 4 KB
    __shared__ float s_wv[Hn];              // 1 KB

    {   // stage k-tile: 32 rows x 64 float4 = 2048 float4, 8 per thread
        const float4* src = reinterpret_cast<const float4*>(
            kproj + ((size_t)b * Kn + k0) * Hn);
        #pragma unroll
        for (int i = 0; i < 8; ++i) {
            int idx = t + i * 256;
            int row = idx >> 6;
            int c4  = idx & 63;
            *reinterpret_cast<float4*>(&s_k[row * SK_PAD + c4 * 4]) = src[idx];
        }
        reinterpret_cast<float4*>(s_q)[t] = reinterpret_cast<const float4*>(
            qproj + ((size_t)b * Qn + q0) * Hn)[t];
        if (t < 64)
            reinterpret_cast<float4*>(s_wv)[t] =
                reinterpret_cast<const float4*>(wv)[t];
    }
    __syncthreads();

    const int wave = t >> 6;
    const int lane = t & 63;
    const int kloc = lane & 31;
    const int hh   = (lane >> 5) * 128;     // h-half: 0 or 128

    const float4* kr = reinterpret_cast<const float4*>(&s_k[kloc * SK_PAD + hh]);
    const float4* qr = reinterpret_cast<const float4*>(&s_q[wave * Hn + hh]);
    const float4* wr = reinterpret_cast<const float4*>(&s_wv[hh]);

    float s = 0.0f;
    #pragma unroll 8
    for (int i = 0; i < 32; ++i) {          // 32 float4 steps = 128 h per lane
        float4 kv = kr[i];
        float4 qv = qr[i];
        float4 wq = wr[i];
        s += wq.x * fast_tanh(qv.x + kv.x);
        s += wq.y * fast_tanh(qv.y + kv.y);
        s += wq.z * fast_tanh(qv.z + kv.z);
        s += wq.w * fast_tanh(qv.w + kv.w);
    }
    s += __shfl_xor(s, 32, 64);             // combine the two h-halves

    if (lane < 32) {
        int k = k0 + lane;
        if (k < vlen)
            scores[((size_t)b * Qn + q0 + wave) * Kn + k] = s;
    }
}

// ---------------------------------------------------------------------------
// Kernel 3: softmax (over staged LDS scores) fused with out = attn @ values.
// Block = (b, 4-q tile, d-half). Normalization folded into epilogue scale.
// ---------------------------------------------------------------------------
#define QT 4
__global__ __launch_bounds__(256) void av_softmax_kernel(
    const float* __restrict__ scores, const float* __restrict__ values,
    const int* __restrict__ valid_lens, float* __restrict__ out)
{
    const int blk = blockIdx.x;             // b(2) | qt(5) | dhalf(1)
    const int dhalf = blk & 1;
    const int qt = (blk >> 1) & 31;
    const int b = blk >> 6;
    const int t = threadIdx.x;
    const int lane = t & 63;
    const int wave = t >> 6;
    const int vlen = valid_lens[b];
    const int q0 = qt * QT;

    __shared__ float s_at[QT][Kn];          // 16 KB
    __shared__ float s_red[2][QT][4];

    #pragma unroll
    for (int j = 0; j < QT; ++j)
        for (int k = t; k < vlen; k += 256)
            s_at[j][k] = scores[((size_t)b * Qn + q0 + j) * Kn + k];
    __syncthreads();

    // ---- row max ----
    float mj[QT];
    #pragma unroll
    for (int j = 0; j < QT; ++j) mj[j] = -1e30f;
    for (int k = t; k < vlen; k += 256) {
        #pragma unroll
        for (int j = 0; j < QT; ++j) mj[j] = fmaxf(mj[j], s_at[j][k]);
    }
    #pragma unroll
    for (int j = 0; j < QT; ++j) {
        #pragma unroll
        for (int off = 32; off; off >>= 1)
            mj[j] = fmaxf(mj[j], __shfl_xor(mj[j], off, 64));
    }
    if (lane == 0) {
        #pragma unroll
        for (int j = 0; j < QT; ++j) s_red[0][j][wave] = mj[j];
    }
    __syncthreads();
    #pragma unroll
    for (int j = 0; j < QT; ++j)
        mj[j] = fmaxf(fmaxf(s_red[0][j][0], s_red[0][j][1]),
                      fmaxf(s_red[0][j][2], s_red[0][j][3]));

    // ---- exp in-place + row sum ----
    float sj[QT] = {0.f, 0.f, 0.f, 0.f};
    for (int k = t; k < vlen; k += 256) {
        #pragma unroll
        for (int j = 0; j < QT; ++j) {
            float e = __expf(s_at[j][k] - mj[j]);
            s_at[j][k] = e;
            sj[j] += e;
        }
    }
    #pragma unroll
    for (int j = 0; j < QT; ++j) {
        #pragma unroll
        for (int off = 32; off; off >>= 1)
            sj[j] += __shfl_xor(sj[j], off, 64);
    }
    if (lane == 0) {
        #pragma unroll
        for (int j = 0; j < QT; ++j) s_red[1][j][wave] = sj[j];
    }
    __syncthreads();                        // also publishes s_at exp values
    float inv[QT];
    #pragma unroll
    for (int j = 0; j < QT; ++j)
        inv[j] = __builtin_amdgcn_rcpf(s_red[1][j][0] + s_red[1][j][1] +
                                       s_red[1][j][2] + s_red[1][j][3]);

    // ---- AV ----
    const float* vb = values + (size_t)b * Kn * Dn + dhalf * 256 + t;
    float acc[QT] = {0.f, 0.f, 0.f, 0.f};
    int k = 0;
    for (; k + 2 <= vlen; k += 2) {
        float v0 = vb[(size_t)k * Dn];
        float v1 = vb[(size_t)(k + 1) * Dn];
        #pragma unroll
        for (int j = 0; j < QT; ++j)
            acc[j] += s_at[j][k] * v0 + s_at[j][k + 1] * v1;
    }
    if (k < vlen) {
        float v0 = vb[(size_t)k * Dn];
        #pragma unroll
        for (int j = 0; j < QT; ++j) acc[j] += s_at[j][k] * v0;
    }
    #pragma unroll
    for (int j = 0; j < QT; ++j)
        out[((size_t)b * Qn + q0 + j) * Dn + dhalf * 256 + t] = acc[j] * inv[j];
}

// ---------------------------------------------------------------------------
extern "C" void kernel_launch(void* const* d_in, const int* in_sizes, int n_in,
                              void* d_out, int out_size, void* d_ws, size_t ws_size,
                              hipStream_t stream) {
    const float* queries    = (const float*)d_in[0];
    const float* keys       = (const float*)d_in[1];
    const float* values     = (const float*)d_in[2];
    const int*   valid_lens = (const int*)  d_in[3];
    const float* Wq         = (const float*)d_in[4];
    const float* Wk         = (const float*)d_in[5];
    const float* wv         = (const float*)d_in[6];
    float* out = (float*)d_out;

    float* qproj  = (float*)d_ws;                 // [B*Q, H]
    float* kproj  = qproj + Bn * Qn * Hn;         // [B*K, H]
    float* scores = kproj + Bn * Kn * Hn;         // [B*Q, K] raw (pre-softmax)

    proj_kernel<<<576, 256, 0, stream>>>(queries, keys, Wq, Wk, valid_lens,
                                         qproj, kproj);
    score_kernel<<<Bn * 32 * 32, 256, 0, stream>>>(qproj, kproj, wv,
                                                   valid_lens, scores);
    av_softmax_kernel<<<256, 256, 0, stream>>>(scores, values, valid_lens, out);
}

// Round 3
// 181.811 us; speedup vs baseline: 1.4973x; 1.0133x over previous
//
#include <hip/hip_runtime.h>

#define Bn 4
#define Qn 128
#define Kn 1024
#define Dn 512   // DQ = DK = DV = 512
#define Hn 256

// tanh(x) = 1 - 2/(1 + e^{2x}).  Inf-safe: e->inf => rcp(inf)=0 => 1; e->0 => -1.
__device__ __forceinline__ float fast_tanh(float x) {
    float e = __expf(2.0f * x);
    return 1.0f - 2.0f * __builtin_amdgcn_rcpf(1.0f + e);
}

// ---------------------------------------------------------------------------
// Kernel 1: projections as register-tiled GEMM. [4608 x 512] @ [512 x 256].
// Block tile 64m x 64n, BK=32, 256 threads, 4x4 acc/thread -> VALU-bound:
// per k-step per wave 2 ds_read_b128 (24cyc) vs 16 FMA (32cyc).
// mt<8 -> queries@Wq; else keys@Wk with fully-masked-tile early exit.
// ---------------------------------------------------------------------------
#define PK 32
#define PApad 68   // stride 68 floats = 272B: 16B-aligned, banks shift by 4/row

__global__ __launch_bounds__(256) void proj_kernel(
    const float* __restrict__ queries, const float* __restrict__ keys,
    const float* __restrict__ Wq, const float* __restrict__ Wk,
    const int* __restrict__ valid_lens,
    float* __restrict__ qproj, float* __restrict__ kproj)
{
    const int blk = blockIdx.x;         // mt(72) * 4 + nt
    const int nt = blk & 3;
    const int mt = blk >> 2;
    const int t = threadIdx.x;
    const float* Asrc; const float* W; float* Dst;
    int m0;
    if (mt < 8) {
        m0 = mt * 64;
        Asrc = queries; W = Wq; Dst = qproj;
    } else {
        int r0 = (mt - 8) * 64;
        int b = r0 >> 10;
        if ((r0 & 1023) >= valid_lens[b]) return;   // tile fully masked
        m0 = r0;
        Asrc = keys; W = Wk; Dst = kproj;
    }
    const int n0 = nt * 64;

    __shared__ float s_a[PK][PApad];    // A^T tile: [k][m]
    __shared__ float s_b[PK][64];       // B tile:   [k][n]

    const int tcol = t & 15;            // 16 col groups x 4
    const int trow = t >> 4;            // 16 row groups x 4

    float acc[4][4] = {{0.f}};

    for (int kt = 0; kt < 16; ++kt) {
        const int d0 = kt * PK;
        #pragma unroll
        for (int i = 0; i < 2; ++i) {   // A: 64 rows x 8 float4
            int idx = t + i * 256;
            int row = idx >> 3;
            int c4  = idx & 7;
            float4 v = *(const float4*)(Asrc + (size_t)(m0 + row) * Dn + d0 + c4 * 4);
            s_a[c4 * 4 + 0][row] = v.x;
            s_a[c4 * 4 + 1][row] = v.y;
            s_a[c4 * 4 + 2][row] = v.z;
            s_a[c4 * 4 + 3][row] = v.w;
        }
        #pragma unroll
        for (int i = 0; i < 2; ++i) {   // B: 32 rows x 16 float4
            int idx = t + i * 256;
            int row = idx >> 4;
            int c4  = idx & 15;
            *(float4*)&s_b[row][c4 * 4] =
                *(const float4*)(W + (size_t)(d0 + row) * Hn + n0 + c4 * 4);
        }
        __syncthreads();
        #pragma unroll 8
        for (int kk = 0; kk < PK; ++kk) {
            float4 a4 = *(const float4*)&s_a[kk][trow * 4];
            float4 b4 = *(const float4*)&s_b[kk][tcol * 4];
            float a[4] = {a4.x, a4.y, a4.z, a4.w};
            float b[4] = {b4.x, b4.y, b4.z, b4.w};
            #pragma unroll
            for (int i = 0; i < 4; ++i) {
                #pragma unroll
                for (int j = 0; j < 4; ++j)
                    acc[i][j] += a[i] * b[j];
            }
        }
        __syncthreads();
    }
    #pragma unroll
    for (int i = 0; i < 4; ++i) {
        float4 o; o.x = acc[i][0]; o.y = acc[i][1]; o.z = acc[i][2]; o.w = acc[i][3];
        *(float4*)(Dst + (size_t)(m0 + trow * 4 + i) * Hn + n0 + tcol * 4) = o;
    }
}

// ---------------------------------------------------------------------------
// Kernel 2: raw scores -> e = exp(score) directly (max-free softmax: |score|
// <= sum|wv| ~ 13, exp cannot overflow) + atomic per-row expsum.
// Block = (b, 4-q tile, 32-k tile); lane pair owns one (q,k), H-loop inside.
// ---------------------------------------------------------------------------
#define SK_KT 32
#define SK_QT 4
#define SK_PAD 260

__global__ __launch_bounds__(256) void score_kernel(
    const float* __restrict__ qproj, const float* __restrict__ kproj,
    const float* __restrict__ wv, const int* __restrict__ valid_lens,
    float* __restrict__ escores, float* __restrict__ rowsum)
{
    const int blk = blockIdx.x;             // b(2) | qt(5) | kt(5)
    const int kt = blk & 31;
    const int qt = (blk >> 5) & 31;
    const int b  = blk >> 10;
    const int vlen = valid_lens[b];
    const int k0 = kt * SK_KT;
    if (k0 >= vlen) return;                 // fully-masked tile: attn==0, skip
    const int q0 = qt * SK_QT;
    const int t = threadIdx.x;

    __shared__ float s_k[SK_KT * SK_PAD];   // 33280 B
    __shared__ float s_q[SK_QT * Hn];       // 4 KB
    __shared__ float s_wv[Hn];              // 1 KB

    {   // stage k-tile: 32 rows x 64 float4
        const float4* src = reinterpret_cast<const float4*>(
            kproj + ((size_t)b * Kn + k0) * Hn);
        #pragma unroll
        for (int i = 0; i < 8; ++i) {
            int idx = t + i * 256;
            int row = idx >> 6;
            int c4  = idx & 63;
            *reinterpret_cast<float4*>(&s_k[row * SK_PAD + c4 * 4]) = src[idx];
        }
        reinterpret_cast<float4*>(s_q)[t] = reinterpret_cast<const float4*>(
            qproj + ((size_t)b * Qn + q0) * Hn)[t];
        if (t < 64)
            reinterpret_cast<float4*>(s_wv)[t] =
                reinterpret_cast<const float4*>(wv)[t];
    }
    __syncthreads();

    const int wave = t >> 6;
    const int lane = t & 63;
    const int kloc = lane & 31;
    const int hh   = (lane >> 5) * 128;     // h-half: 0 or 128

    const float4* kr = reinterpret_cast<const float4*>(&s_k[kloc * SK_PAD + hh]);
    const float4* qr = reinterpret_cast<const float4*>(&s_q[wave * Hn + hh]);
    const float4* wr = reinterpret_cast<const float4*>(&s_wv[hh]);

    float s = 0.0f;
    #pragma unroll 8
    for (int i = 0; i < 32; ++i) {          // 32 float4 steps = 128 h per lane
        float4 kv = kr[i];
        float4 qv = qr[i];
        float4 wq = wr[i];
        s += wq.x * fast_tanh(qv.x + kv.x);
        s += wq.y * fast_tanh(qv.y + kv.y);
        s += wq.z * fast_tanh(qv.z + kv.z);
        s += wq.w * fast_tanh(qv.w + kv.w);
    }
    s += __shfl_xor(s, 32, 64);             // combine the two h-halves

    const int k = k0 + (lane & 31);
    float e = 0.0f;
    if (lane < 32 && k < vlen) {
        e = __expf(s);                      // no max subtraction needed
        escores[((size_t)b * Qn + q0 + wave) * Kn + k] = e;
    }
    // wave-level expsum (lanes 32..63 carry 0 -> full butterfly is exact)
    #pragma unroll
    for (int off = 32; off; off >>= 1)
        e += __shfl_xor(e, off, 64);
    if (lane == 0)
        atomicAdd(&rowsum[b * Qn + q0 + wave], e);
}

// ---------------------------------------------------------------------------
// Kernel 3: out = (e / rowsum) @ values. Block = (b, 8-q tile, 128-d quarter),
// 256 blocks, 2 in-block k-slices reduced via LDS (no atomics, no out-zero).
// e staged in LDS; broadcast float4 reads; values reads coalesced.
// ---------------------------------------------------------------------------
#define AQT 8
__global__ __launch_bounds__(256) void av_kernel(
    const float* __restrict__ escores, const float* __restrict__ rowsum,
    const float* __restrict__ values, const int* __restrict__ valid_lens,
    float* __restrict__ out)
{
    const int blk = blockIdx.x;         // ((b*16 + qt)*4 + dq)
    const int dq = blk & 3;
    const int qt = (blk >> 2) & 15;
    const int b  = blk >> 6;
    const int t = threadIdx.x;
    const int vlen = valid_lens[b];
    const int q0 = qt * AQT;
    const int d0 = dq * 128;
    const int col = t & 127;
    const int slice = t >> 7;           // waves 0-1: slice 0, waves 2-3: slice 1

    __shared__ float s_e[AQT][Kn];      // 32 KB
    __shared__ float s_red[128][AQT + 1];

    {   // stage 8 e-rows (poison past vlen is never read: loops bounded)
        const float4* src = reinterpret_cast<const float4*>(
            escores + (size_t)(b * Qn + q0) * Kn);
        float4* dst = reinterpret_cast<float4*>(s_e);
        #pragma unroll
        for (int i = 0; i < 8; ++i)
            dst[t + i * 256] = src[t + i * 256];
    }
    __syncthreads();

    float inv[AQT];
    #pragma unroll
    for (int j = 0; j < AQT; ++j)
        inv[j] = __builtin_amdgcn_rcpf(rowsum[b * Qn + q0 + j]);

    // k-slices: [0, kh) and [kh, vlen), kh 4-aligned for float4 LDS reads
    int kh = (vlen >> 1) + 3;
    kh &= ~3;
    if (kh > vlen) kh = vlen;
    const int ks = slice ? kh : 0;
    const int ke = slice ? vlen : kh;

    const float* vb = values + (size_t)b * Kn * Dn + d0 + col;
    float acc[AQT] = {0.f};
    int k = ks;
    for (; k + 4 <= ke; k += 4) {
        float v0 = vb[(size_t)(k + 0) * Dn];
        float v1 = vb[(size_t)(k + 1) * Dn];
        float v2 = vb[(size_t)(k + 2) * Dn];
        float v3 = vb[(size_t)(k + 3) * Dn];
        #pragma unroll
        for (int j = 0; j < AQT; ++j) {
            float4 e4 = *(const float4*)&s_e[j][k];   // broadcast, 16B-aligned
            acc[j] += e4.x * v0 + e4.y * v1 + e4.z * v2 + e4.w * v3;
        }
    }
    for (; k < ke; ++k) {               // tail
        float v0 = vb[(size_t)k * Dn];
        #pragma unroll
        for (int j = 0; j < AQT; ++j)
            acc[j] += s_e[j][k] * v0;
    }

    if (slice == 1) {
        #pragma unroll
        for (int j = 0; j < AQT; ++j) s_red[col][j] = acc[j];
    }
    __syncthreads();
    if (slice == 0) {
        #pragma unroll
        for (int j = 0; j < AQT; ++j) {
            float r = (acc[j] + s_red[col][j]) * inv[j];
            out[(size_t)(b * Qn + q0 + j) * Dn + d0 + col] = r;
        }
    }
}

// ---------------------------------------------------------------------------
extern "C" void kernel_launch(void* const* d_in, const int* in_sizes, int n_in,
                              void* d_out, int out_size, void* d_ws, size_t ws_size,
                              hipStream_t stream) {
    const float* queries    = (const float*)d_in[0];
    const float* keys       = (const float*)d_in[1];
    const float* values     = (const float*)d_in[2];
    const int*   valid_lens = (const int*)  d_in[3];
    const float* Wq         = (const float*)d_in[4];
    const float* Wk         = (const float*)d_in[5];
    const float* wv         = (const float*)d_in[6];
    float* out = (float*)d_out;

    float* qproj   = (float*)d_ws;                // [B*Q, H]   131072 f
    float* kproj   = qproj + Bn * Qn * Hn;        // [B*K, H]  1048576 f
    float* escores = kproj + Bn * Kn * Hn;        // [B*Q, K]   524288 f
    float* rowsum  = escores + Bn * Qn * Kn;      // [B*Q]         512 f

    hipMemsetAsync(rowsum, 0, Bn * Qn * sizeof(float), stream);
    proj_kernel<<<288, 256, 0, stream>>>(queries, keys, Wq, Wk, valid_lens,
                                         qproj, kproj);
    score_kernel<<<Bn * 32 * 32, 256, 0, stream>>>(qproj, kproj, wv,
                                                   valid_lens, escores, rowsum);
    av_kernel<<<256, 256, 0, stream>>>(escores, rowsum, values, valid_lens, out);
}

// Round 4
// 171.157 us; speedup vs baseline: 1.5905x; 1.0622x over previous
//
#include <hip/hip_runtime.h>

#define Bn 4
#define Qn 128
#define Kn 1024
#define Dn 512   // DQ = DK = DV = 512
#define Hn 256

// tanh(x) = 1 - 2/(1 + e^{2x}).  Inf-safe: e->inf => rcp(inf)=0 => 1.
__device__ __forceinline__ float fast_tanh(float x) {
    float e = __expf(2.0f * x);
    return 1.0f - 2.0f * __builtin_amdgcn_rcpf(1.0f + e);
}

// ---------------------------------------------------------------------------
// Kernel 1: projections GEMM [4608x512]@[512x256], 64x64 tile, BK=64,
// register double-buffer prefetch: next k-tile loads issue before the compute
// phase, vmcnt-waited only at the next LDS store -> 2048 cyc of compute cover
// the L2 latency even at ~1 block/CU.
// ---------------------------------------------------------------------------
#define PBK 64

__global__ __launch_bounds__(256) void proj_kernel(
    const float* __restrict__ queries, const float* __restrict__ keys,
    const float* __restrict__ Wq, const float* __restrict__ Wk,
    const int* __restrict__ valid_lens,
    float* __restrict__ qproj, float* __restrict__ kproj)
{
    const int blk = blockIdx.x;         // mt(72) * 4 + nt
    const int nt = blk & 3;
    const int mt = blk >> 2;
    const int t = threadIdx.x;
    const float* Asrc; const float* W; float* Dst;
    int m0;
    if (mt < 8) {
        m0 = mt * 64;
        Asrc = queries; W = Wq; Dst = qproj;
    } else {
        int r0 = (mt - 8) * 64;
        int b = r0 >> 10;
        if ((r0 & 1023) >= valid_lens[b]) return;   // tile fully masked
        m0 = r0;
        Asrc = keys; W = Wk; Dst = kproj;
    }
    const int n0 = nt * 64;

    __shared__ float s_a[PBK][68];      // A^T tile [k][m], pad 68
    __shared__ float s_b[PBK][64];      // B tile   [k][n]

    const int trow = t >> 4;            // 0..15 (x4 m)
    const int tcol = t & 15;            // 0..15 (x4 n)

    float acc[4][4] = {{0.f}};
    float4 ra[4], rb[4];

    #pragma unroll
    for (int i = 0; i < 4; ++i) {       // preload kt=0
        int row = (t >> 4) + i * 16, c4 = t & 15;
        ra[i] = *(const float4*)(Asrc + (size_t)(m0 + row) * Dn + c4 * 4);
        rb[i] = *(const float4*)(W + (size_t)row * Hn + n0 + c4 * 4);
    }

    for (int kt = 0; kt < 8; ++kt) {
        __syncthreads();                // prev compute done before overwrite
        #pragma unroll
        for (int i = 0; i < 4; ++i) {   // regs -> LDS (waits vmcnt here)
            int row = (t >> 4) + i * 16, c4 = t & 15;
            s_a[c4 * 4 + 0][row] = ra[i].x;
            s_a[c4 * 4 + 1][row] = ra[i].y;
            s_a[c4 * 4 + 2][row] = ra[i].z;
            s_a[c4 * 4 + 3][row] = ra[i].w;
            *(float4*)&s_b[row][c4 * 4] = rb[i];
        }
        __syncthreads();
        if (kt < 7) {                   // prefetch kt+1 (overlaps compute)
            const int d0n = (kt + 1) * PBK;
            #pragma unroll
            for (int i = 0; i < 4; ++i) {
                int row = (t >> 4) + i * 16, c4 = t & 15;
                ra[i] = *(const float4*)(Asrc + (size_t)(m0 + row) * Dn + d0n + c4 * 4);
                rb[i] = *(const float4*)(W + (size_t)(d0n + row) * Hn + n0 + c4 * 4);
            }
        }
        #pragma unroll 16
        for (int kk = 0; kk < PBK; ++kk) {
            float4 a4 = *(const float4*)&s_a[kk][trow * 4];
            float4 b4 = *(const float4*)&s_b[kk][tcol * 4];
            float a[4] = {a4.x, a4.y, a4.z, a4.w};
            float b[4] = {b4.x, b4.y, b4.z, b4.w};
            #pragma unroll
            for (int i = 0; i < 4; ++i)
                #pragma unroll
                for (int j = 0; j < 4; ++j)
                    acc[i][j] += a[i] * b[j];
        }
    }
    #pragma unroll
    for (int i = 0; i < 4; ++i) {
        float4 o; o.x = acc[i][0]; o.y = acc[i][1]; o.z = acc[i][2]; o.w = acc[i][3];
        *(float4*)(Dst + (size_t)(m0 + trow * 4 + i) * Hn + n0 + tcol * 4) = o;
    }
}

// ---------------------------------------------------------------------------
// Kernel 2: e = exp(score) (max-free: |score| <= sum|wv|) + atomic rowsum.
// k-tile = 16 (LDS 21.8 KB -> 7 blocks/CU), lane = kloc(16) x h-quarter(4),
// each lane sums 64 h; two shfl_xor combine. Grid 8192, ~11 active blocks/CU.
// ---------------------------------------------------------------------------
#define SK_KT 16
#define SK_PAD 260

__global__ __launch_bounds__(256) void score_kernel(
    const float* __restrict__ qproj, const float* __restrict__ kproj,
    const float* __restrict__ wv, const int* __restrict__ valid_lens,
    float* __restrict__ escores, float* __restrict__ rowsum)
{
    const int blk = blockIdx.x;             // ((b*32 + qt)*64 + kt)
    const int kt = blk & 63;
    const int qt = (blk >> 6) & 31;
    const int b  = blk >> 11;
    const int vlen = valid_lens[b];
    const int k0 = kt * SK_KT;
    if (k0 >= vlen) return;                 // fully-masked tile
    const int q0 = qt * 4;
    const int t = threadIdx.x;

    __shared__ float s_k[SK_KT * SK_PAD];   // 16640 B
    __shared__ float s_q[4 * Hn];           // 4 KB
    __shared__ float s_wv[Hn];              // 1 KB

    {
        const float4* src = reinterpret_cast<const float4*>(
            kproj + ((size_t)b * Kn + k0) * Hn);
        #pragma unroll
        for (int i = 0; i < 4; ++i) {       // 16 rows x 64 float4
            int idx = t + i * 256;
            int row = idx >> 6, c4 = idx & 63;
            *reinterpret_cast<float4*>(&s_k[row * SK_PAD + c4 * 4]) = src[idx];
        }
        reinterpret_cast<float4*>(s_q)[t] = reinterpret_cast<const float4*>(
            qproj + ((size_t)b * Qn + q0) * Hn)[t];
        if (t < 64)
            reinterpret_cast<float4*>(s_wv)[t] =
                reinterpret_cast<const float4*>(wv)[t];
    }
    __syncthreads();

    const int wave = t >> 6;
    const int lane = t & 63;
    const int kloc = lane & 15;
    const int hq   = lane >> 4;             // h-quarter: 64 h each

    const float4* kr = reinterpret_cast<const float4*>(&s_k[kloc * SK_PAD + hq * 64]);
    const float4* qr = reinterpret_cast<const float4*>(&s_q[wave * Hn + hq * 64]);
    const float4* wr = reinterpret_cast<const float4*>(&s_wv[hq * 64]);

    float s = 0.0f;
    #pragma unroll
    for (int i = 0; i < 16; ++i) {          // 16 float4 = 64 h per lane
        float4 kv = kr[i];
        float4 qv = qr[i];
        float4 wq = wr[i];
        s += wq.x * fast_tanh(qv.x + kv.x);
        s += wq.y * fast_tanh(qv.y + kv.y);
        s += wq.z * fast_tanh(qv.z + kv.z);
        s += wq.w * fast_tanh(qv.w + kv.w);
    }
    s += __shfl_xor(s, 16, 64);
    s += __shfl_xor(s, 32, 64);

    const int k = k0 + kloc;
    float e = 0.0f;
    if (lane < 16 && k < vlen) {
        e = __expf(s);
        escores[((size_t)b * Qn + q0 + wave) * Kn + k] = e;
    }
    #pragma unroll
    for (int off = 32; off; off >>= 1)
        e += __shfl_xor(e, off, 64);
    if (lane == 0)
        atomicAdd(&rowsum[b * Qn + q0 + wave], e);
}

// ---------------------------------------------------------------------------
// Kernel 3a: uniform split-k AV partials. escores fully zeroed -> masked k
// contribute 0 -> NO vlen dependence, free grid shaping, zero imbalance.
// Block = (b, 8q, 256d-half, 256k-chunk) = 512 blocks. 8 loads in flight.
// Partials land in ws (reuses the dead kproj region).
// ---------------------------------------------------------------------------
__global__ __launch_bounds__(256) void av_part_kernel(
    const float* __restrict__ escores, const float* __restrict__ values,
    float* __restrict__ parts)
{
    const int blk = blockIdx.x;         // (((b*16+qt)*2+dh)*4+kc)
    const int kc = blk & 3;
    const int dh = (blk >> 2) & 1;
    const int qt = (blk >> 3) & 15;
    const int b  = blk >> 7;
    const int t = threadIdx.x;
    const int q0 = qt * 8;
    const int kb = kc * 256;
    const int d  = dh * 256 + t;

    __shared__ float s_e[8][256];       // 8 KB
    #pragma unroll
    for (int i = 0; i < 2; ++i) {
        int idx = t + i * 256;
        int row = idx >> 6, c4 = idx & 63;
        *(float4*)&s_e[row][c4 * 4] = *(const float4*)(
            escores + ((size_t)(b * Qn + q0 + row)) * Kn + kb + c4 * 4);
    }
    __syncthreads();

    const float* vb = values + ((size_t)b * Kn + kb) * Dn + d;
    float acc[8] = {0.f};
    #pragma unroll 2
    for (int k = 0; k < 256; k += 4) {
        float v0 = vb[(size_t)(k + 0) * Dn];
        float v1 = vb[(size_t)(k + 1) * Dn];
        float v2 = vb[(size_t)(k + 2) * Dn];
        float v3 = vb[(size_t)(k + 3) * Dn];
        #pragma unroll
        for (int j = 0; j < 8; ++j) {
            float4 e4 = *(const float4*)&s_e[j][k];  // wave-uniform broadcast
            acc[j] += e4.x * v0 + e4.y * v1 + e4.z * v2 + e4.w * v3;
        }
    }
    float* pp = parts + (size_t)kc * (Bn * Qn * Dn)
                      + ((size_t)(b * Qn + q0)) * Dn + d;
    #pragma unroll
    for (int j = 0; j < 8; ++j)
        pp[(size_t)j * Dn] = acc[j];
}

// ---------------------------------------------------------------------------
// Kernel 3b: out = (sum of 4 partials) * rcp(rowsum[row]).
// ---------------------------------------------------------------------------
__global__ __launch_bounds__(256) void reduce_kernel(
    const float* __restrict__ parts, const float* __restrict__ rowsum,
    float* __restrict__ out)
{
    const int idx = blockIdx.x * 256 + threadIdx.x;   // float4 index, 65536 total
    const int row = (idx * 4) >> 9;                   // / Dn
    const float inv = __builtin_amdgcn_rcpf(rowsum[row]);
    const float4* p = (const float4*)parts;
    float4 a = p[idx];
    float4 b = p[idx + 65536];
    float4 c = p[idx + 131072];
    float4 d = p[idx + 196608];
    float4 o;
    o.x = (a.x + b.x + c.x + d.x) * inv;
    o.y = (a.y + b.y + c.y + d.y) * inv;
    o.z = (a.z + b.z + c.z + d.z) * inv;
    o.w = (a.w + b.w + c.w + d.w) * inv;
    ((float4*)out)[idx] = o;
}

// ---------------------------------------------------------------------------
extern "C" void kernel_launch(void* const* d_in, const int* in_sizes, int n_in,
                              void* d_out, int out_size, void* d_ws, size_t ws_size,
                              hipStream_t stream) {
    const float* queries    = (const float*)d_in[0];
    const float* keys       = (const float*)d_in[1];
    const float* values     = (const float*)d_in[2];
    const int*   valid_lens = (const int*)  d_in[3];
    const float* Wq         = (const float*)d_in[4];
    const float* Wk         = (const float*)d_in[5];
    const float* wv         = (const float*)d_in[6];
    float* out = (float*)d_out;

    float* qproj   = (float*)d_ws;                // [B*Q, H]     131072 f
    float* kproj   = qproj + Bn * Qn * Hn;        // [B*K, H]    1048576 f
    float* escores = kproj + Bn * Kn * Hn;        // [B*Q, K]     524288 f
    float* rowsum  = escores + Bn * Qn * Kn;      // [B*Q]           512 f
    float* parts   = kproj;                       // alias: kproj dead after score
                                                  // 4*[B*Q,D] = 1048576 f (fits)

    // zero escores (masked k stay 0) + rowsum in one memset
    hipMemsetAsync(escores, 0, (size_t)(Bn * Qn * Kn + Bn * Qn) * sizeof(float),
                   stream);
    proj_kernel<<<288, 256, 0, stream>>>(queries, keys, Wq, Wk, valid_lens,
                                         qproj, kproj);
    score_kernel<<<Bn * 32 * 64, 256, 0, stream>>>(qproj, kproj, wv,
                                                   valid_lens, escores, rowsum);
    av_part_kernel<<<512, 256, 0, stream>>>(escores, values, parts);
    reduce_kernel<<<256, 256, 0, stream>>>(parts, rowsum, out);
}